// Round 15
// baseline (100.313 us; speedup 1.0000x reference)
//
#include <hip/hip_runtime.h>
#include <hip/hip_bf16.h>
#include <math.h>

#define B_     32
#define HID_   768
#define OUT5_  2304
#define HDIM_  512
#define NC_    65536
#define MAXG_  11
#define NL_    670091
#define TOPK_  10
#define CAND_  110   // TOPK_*MAXG_
#define NOUT_  3520  // B_*CAND_

__device__ __forceinline__ float gelu_exact(float x){
  return 0.5f * x * (1.0f + erff(x * 0.70710678118654752440f));
}

__device__ __forceinline__ unsigned long long packv(float x, int col){
  unsigned u = __float_as_uint(x);
  u = (u & 0x80000000u) ? ~u : (u | 0x80000000u);   // order-preserving float->uint
  return (((unsigned long long)u) << 16) | (unsigned long long)(65535 - col); // tie -> lower col wins
}

__device__ __forceinline__ float unpack_val(unsigned long long g){
  unsigned u = (unsigned)(g >> 16);
  unsigned bits = (u & 0x80000000u) ? (u & 0x7FFFFFFFu) : ~u;
  return __uint_as_float(bits);
}

__device__ __forceinline__ int unpack_col(unsigned long long g){
  return 65535 - (int)(g & 0xFFFFULL);
}

__device__ __forceinline__ unsigned long long block_max_u64(unsigned long long m,
                                                            unsigned long long* sm, int nwaves){
  #pragma unroll
  for (int off = 1; off < 64; off <<= 1){
    unsigned long long o = __shfl_xor(m, off);
    if (o > m) m = o;
  }
  const int tid = threadIdx.x;
  if ((tid & 63) == 0) sm[tid >> 6] = m;
  __syncthreads();
  unsigned long long g = sm[0];
  for (int w = 1; w < nwaves; ++w) if (sm[w] > g) g = sm[w];
  __syncthreads();
  return g;
}

typedef const __attribute__((address_space(1))) void* gas_t;
typedef __attribute__((address_space(3))) void* las_t;
__device__ __forceinline__ void gload_lds16(const float* g, float* l){
  __builtin_amdgcn_global_load_lds((gas_t)(const void*)g, (las_t)(void*)l, 16, 0, 0);
}

// K1: partial sums for the two small GEMMs (R14, unchanged).
__global__ __launch_bounds__(256)
void mlp_partial(const float* __restrict__ hidf, const float* __restrict__ hidl5,
                 const float* __restrict__ W1, const float* __restrict__ Wext,
                 float* __restrict__ partial){
  const int jl  = threadIdx.x & 63;
  const int bq  = threadIdx.x >> 6;
  const int col = blockIdx.x * 64 + jl;
  const int chunk = blockIdx.y;
  const float* W; const float* X; int Kfull, k0;
  if (chunk < 8){ W = W1;   X = hidf;  Kfull = HID_;  k0 = chunk * 96; }
  else          { W = Wext; X = hidl5; Kfull = OUT5_; k0 = (chunk - 8) * 96; }
  const float* Wp = W + (size_t)k0 * HDIM_ + col;
  const float* Xp = X + (size_t)(bq * 8) * Kfull + k0;
  float acc[8] = {0,0,0,0,0,0,0,0};
  for (int k = 0; k < 96; k += 8){
    float wv[8];
    #pragma unroll
    for (int u = 0; u < 8; ++u) wv[u] = Wp[(size_t)(k + u) * HDIM_];
    #pragma unroll
    for (int i = 0; i < 8; ++i){
      const float4 xa = *reinterpret_cast<const float4*>(Xp + (size_t)i * Kfull + k);
      const float4 xb = *reinterpret_cast<const float4*>(Xp + (size_t)i * Kfull + k + 4);
      acc[i] = fmaf(xa.x, wv[0], acc[i]);
      acc[i] = fmaf(xa.y, wv[1], acc[i]);
      acc[i] = fmaf(xa.z, wv[2], acc[i]);
      acc[i] = fmaf(xa.w, wv[3], acc[i]);
      acc[i] = fmaf(xb.x, wv[4], acc[i]);
      acc[i] = fmaf(xb.y, wv[5], acc[i]);
      acc[i] = fmaf(xb.z, wv[6], acc[i]);
      acc[i] = fmaf(xb.w, wv[7], acc[i]);
    }
  }
  float* outp = partial + (size_t)chunk * (B_ * HDIM_) + (size_t)(bq * 8) * HDIM_ + col;
  #pragma unroll
  for (int i = 0; i < 8; ++i) outp[(size_t)i * HDIM_] = acc[i];
}

// K2: reduce chunks + bias + exact GELU (R14, unchanged).
__global__ __launch_bounds__(256)
void act_kernel(const float* __restrict__ partial, const float* __restrict__ b1,
                const float* __restrict__ bext, float* __restrict__ hT,
                float* __restrict__ h_ext){
  const int t = blockIdx.x * 256 + threadIdx.x;
  if (t < B_ * HDIM_){
    const int b = t >> 9, j = t & 511;
    float s = b1[j];
    #pragma unroll
    for (int c = 0; c < 8; ++c) s += partial[c * (B_ * HDIM_) + t];
    hT[j * B_ + b] = gelu_exact(s);
  } else {
    const int u = t - B_ * HDIM_;
    const int j = u & 511;
    float s = bext[j];
    #pragma unroll
    for (int c = 8; c < 32; ++c) s += partial[c * (B_ * HDIM_) + u];
    h_ext[u] = gelu_exact(s);
  }
}

// K3: meta GEMM, triple-buffered counted-vmcnt pipeline + uniform-hT s_loads (R13, unchanged).
#define CKM_ 32
__global__ __launch_bounds__(1024, 4)
void meta_gemm(const float* __restrict__ hT, const float* __restrict__ W2,
               const float* __restrict__ b2, float* __restrict__ logits){
  __shared__ float smem[3][CKM_ * 256];   // 3 x 32 KB = 96 KB
  const int tid = threadIdx.x;
  const int l   = tid & 63;
  const int w   = tid >> 6;               // 0..15
  const int r   = w & 3;                  // row-group
  const int q   = w >> 2;                 // k-quarter
  const int colBase = blockIdx.x * 256;
  const int sb8 = __builtin_amdgcn_readfirstlane(r * 8);
  const int kb8 = __builtin_amdgcn_readfirstlane(q * 8);   // uniform k-offset

  float acc[8][4];
  #pragma unroll
  for (int i = 0; i < 8; ++i)
    #pragma unroll
    for (int j = 0; j < 4; ++j) acc[i][j] = 0.f;

  auto stage = [&](int c, int bf){
    #pragma unroll
    for (int i = 0; i < 2; ++i){
      const int row = 2 * w + i;
      gload_lds16(W2 + (size_t)(c * CKM_ + row) * NC_ + colBase + l * 4,
                  &smem[bf][row * 256]);
    }
  };

  auto compute = [&](int c, int bf){
    const float* __restrict__ hbase = hT + (size_t)(c * CKM_ + kb8) * B_ + sb8;
    #pragma unroll
    for (int kk = 0; kk < 8; ++kk){
      const float4 wv = *reinterpret_cast<const float4*>(&smem[bf][(kb8 + kk) * 256 + l * 4]);
      const float4 h0 = *reinterpret_cast<const float4*>(hbase + kk * B_);
      const float4 h1 = *reinterpret_cast<const float4*>(hbase + kk * B_ + 4);
      const float hv[8] = {h0.x, h0.y, h0.z, h0.w, h1.x, h1.y, h1.z, h1.w};
      #pragma unroll
      for (int row = 0; row < 8; ++row){
        acc[row][0] = fmaf(hv[row], wv.x, acc[row][0]);
        acc[row][1] = fmaf(hv[row], wv.y, acc[row][1]);
        acc[row][2] = fmaf(hv[row], wv.z, acc[row][2]);
        acc[row][3] = fmaf(hv[row], wv.w, acc[row][3]);
      }
    }
  };

  stage(0, 0);
  stage(1, 1);
  for (int c = 0; c < HDIM_ / CKM_ - 1; ++c){   // c = 0..14
    asm volatile("s_waitcnt vmcnt(2)" ::: "memory");  // chunk c landed; c+1 in flight
    __builtin_amdgcn_s_barrier();
    if (c + 2 < HDIM_ / CKM_) stage(c + 2, (c + 2) % 3);
    compute(c, c % 3);
  }
  asm volatile("s_waitcnt vmcnt(0)" ::: "memory");
  __builtin_amdgcn_s_barrier();
  compute(HDIM_ / CKM_ - 1, (HDIM_ / CKM_ - 1) % 3);
  __syncthreads();

  // cross-quarter reduction through smem[0], 3 rounds.
  #pragma unroll
  for (int qq = 1; qq <= 3; ++qq){
    if (q == qq){
      #pragma unroll
      for (int row = 0; row < 8; ++row){
        float4 t; t.x = acc[row][0]; t.y = acc[row][1]; t.z = acc[row][2]; t.w = acc[row][3];
        *reinterpret_cast<float4*>(&smem[0][(r * 8 + row) * 256 + l * 4]) = t;
      }
    }
    __syncthreads();
    if (q == 0){
      #pragma unroll
      for (int row = 0; row < 8; ++row){
        const float4 t = *reinterpret_cast<const float4*>(&smem[0][(r * 8 + row) * 256 + l * 4]);
        acc[row][0] += t.x; acc[row][1] += t.y; acc[row][2] += t.z; acc[row][3] += t.w;
      }
    }
    __syncthreads();
  }

  if (q == 0){
    const float4 bb = *reinterpret_cast<const float4*>(b2 + colBase + l * 4);
    #pragma unroll
    for (int row = 0; row < 8; ++row){
      float4 o;
      o.x = acc[row][0] + bb.x; o.y = acc[row][1] + bb.y;
      o.z = acc[row][2] + bb.z; o.w = acc[row][3] + bb.w;
      *reinterpret_cast<float4*>(logits + (size_t)(sb8 + row) * NC_ + colBase + l * 4) = o;
    }
  }
}

// K4: per-(row, 8192-col segment) top-10 (R4, unchanged).
__global__ __launch_bounds__(256)
void topk_seg(const float* __restrict__ logits, float* __restrict__ segv,
              int* __restrict__ segi){
  __shared__ unsigned long long sm[4];
  const int b   = blockIdx.x >> 3;
  const int seg = blockIdx.x & 7;
  const int tid = threadIdx.x;
  const float* row = logits + (size_t)b * NC_ + seg * 8192;
  float v[10]; int ix[10];
  #pragma unroll
  for (int r = 0; r < 10; ++r){ v[r] = -INFINITY; ix[r] = -1; }
  for (int s = 0; s < 32; ++s){
    const int j = s * 256 + tid;
    const float x = row[j];
    if (x > v[9]){
      v[9] = x; ix[9] = seg * 8192 + j;
      #pragma unroll
      for (int p = 9; p > 0; --p){
        if (v[p] > v[p-1]){
          float tv = v[p]; v[p] = v[p-1]; v[p-1] = tv;
          int   ti = ix[p]; ix[p] = ix[p-1]; ix[p-1] = ti;
        }
      }
    }
  }
  for (int r = 0; r < 10; ++r){
    unsigned long long mp = (ix[0] >= 0) ? packv(v[0], ix[0]) : 0ULL;
    unsigned long long g  = block_max_u64(mp, sm, 4);
    if (mp == g && mp != 0ULL){
      #pragma unroll
      for (int q = 0; q < 9; ++q){ v[q] = v[q+1]; ix[q] = ix[q+1]; }
      v[9] = -INFINITY; ix[9] = -1;
    }
    if (tid == 0){
      segv[blockIdx.x * 10 + r] = unpack_val(g);
      segi[blockIdx.x * 10 + r] = unpack_col(g);
    }
  }
}

// K5 (fused): per-row { merge 80->10 | candidate gather/dot/outputs }.
// 32 blocks x 1024 thr (16 waves). Phase 1 = R6 stage-D2 merge; phase 2 = R5 cand phase.
__global__ __launch_bounds__(1024)
void merge_cand(const float* __restrict__ segv, const int* __restrict__ segi,
                const int* __restrict__ gy, const float* __restrict__ embed,
                const float* __restrict__ h_ext, float* __restrict__ out_f){
  __shared__ unsigned long long smx[16];
  __shared__ int   tk_i[TOPK_];
  __shared__ float tk_s[TOPK_];
  const int b    = blockIdx.x;
  const int tid  = threadIdx.x;
  const int lane = tid & 63;
  const int w    = tid >> 6;                        // 0..15

  // Phase 1: merge 8 segment top-10s (80 packed keys) -> global top-10.
  unsigned long long mp = 0ULL;
  if (tid < 80) mp = packv(segv[b * 80 + tid], segi[b * 80 + tid]);
  for (int r = 0; r < 10; ++r){
    unsigned long long wm = mp;
    #pragma unroll
    for (int off = 1; off < 64; off <<= 1){
      unsigned long long o = __shfl_xor(wm, off);
      if (o > wm) wm = o;
    }
    if (lane == 0) smx[w] = wm;
    __syncthreads();
    unsigned long long g = smx[0];
    #pragma unroll
    for (int qq = 1; qq < 16; ++qq) if (smx[qq] > g) g = smx[qq];
    if (mp == g && g != 0ULL) mp = 0ULL;            // consumed (keys distinct)
    if (tid == 0){
      tk_i[r] = unpack_col(g);
      tk_s[r] = 1.0f / (1.0f + expf(-unpack_val(g)));
    }
    __syncthreads();
  }

  // Phase 2: wave w handles candidate slots c = w, w+16, ...
  const unsigned int* gyw = (const unsigned int*)gy;
  const unsigned int probe = gyw[2 * (size_t)((b * 16 + w) * 64 + lane) + 1];
  const bool is64 = (__ballot(probe != 0u) == 0ULL);  // int64 vs int32 group_y

  const float* hrow = h_ext + (size_t)b * HDIM_;
  const float4 h0 = reinterpret_cast<const float4*>(hrow)[lane];
  const float4 h1 = reinterpret_cast<const float4*>(hrow)[lane + 64];
  __hip_bfloat16* outs = (__hip_bfloat16*)(out_f + NOUT_);
  __hip_bfloat16* outm = outs + NOUT_;

  for (int c = w; c < CAND_; c += 16){
    const int t = c / MAXG_;
    const int g = c - t * MAXG_;
    const int idx = tk_i[t];
    const size_t li = (size_t)idx * MAXG_ + g;
    const int cand = is64 ? (int)((const long long*)gy)[li] : gy[li];
    const float* erow = embed + (size_t)cand * HDIM_;
    const float4 e0 = reinterpret_cast<const float4*>(erow)[lane];
    const float4 e1 = reinterpret_cast<const float4*>(erow)[lane + 64];
    float s = e0.x*h0.x + e0.y*h0.y + e0.z*h0.z + e0.w*h0.w
            + e1.x*h1.x + e1.y*h1.y + e1.z*h1.z + e1.w*h1.w;
    #pragma unroll
    for (int off = 1; off < 64; off <<= 1) s += __shfl_xor(s, off);
    if (lane == 0){
      const float cs   = (s == 0.0f) ? 0.0f : 1.0f / (1.0f + expf(-s));
      const float comb = cs * ((cand != NL_) ? tk_s[t] : 0.0f);
      const int o = b * CAND_ + c;
      out_f[o] = (float)cand;
      outs[o]  = __float2bfloat16(cs);
      outm[o]  = __float2bfloat16(comb);
    }
  }
}

extern "C" void kernel_launch(void* const* d_in, const int* in_sizes, int n_in,
                              void* d_out, int out_size, void* d_ws, size_t ws_size,
                              hipStream_t stream){
  const float* hidf  = (const float*)d_in[0];
  const float* hidl5 = (const float*)d_in[1];
  const float* W1    = (const float*)d_in[2];
  const float* b1    = (const float*)d_in[3];
  const float* W2    = (const float*)d_in[4];
  const float* b2    = (const float*)d_in[5];
  const float* Wext  = (const float*)d_in[6];
  const float* bext  = (const float*)d_in[7];
  const float* embed = (const float*)d_in[8];
  const int*   gy    = (const int*)d_in[9];
  float* out_f = (float*)d_out;

  float* ws      = (float*)d_ws;
  float* logits  = ws;                          // [32][65536] f32 (8 MiB)
  float* partial = ws;                          // aliased: dead before meta_gemm
  float* hT      = logits + (size_t)B_ * NC_;   // [512][32]
  float* h_ext   = hT + B_ * HDIM_;             // [32][512]
  float* segv    = h_ext + B_ * HDIM_;          // 2560
  int*   segi    = (int*)(segv + 2560);         // 2560

  mlp_partial<<<dim3(8, 32), 256, 0, stream>>>(hidf, hidl5, W1, Wext, partial);
  act_kernel <<<128, 256, 0, stream>>>(partial, b1, bext, hT, h_ext);
  meta_gemm  <<<NC_ / 256, 1024, 0, stream>>>(hT, W2, b2, logits);
  topk_seg   <<<B_ * 8, 256, 0, stream>>>(logits, segv, segi);
  merge_cand <<<B_, 1024, 0, stream>>>(segv, segi, gy, embed, h_ext, out_f);
}

// Round 16
// 86.860 us; speedup vs baseline: 1.1549x; 1.1549x over previous
//
#include <hip/hip_runtime.h>
#include <hip/hip_bf16.h>
#include <math.h>

#define B_     32
#define HID_   768
#define OUT5_  2304
#define HDIM_  512
#define NC_    65536
#define MAXG_  11
#define NL_    670091
#define TOPK_  10
#define CAND_  110   // TOPK_*MAXG_
#define NOUT_  3520  // B_*CAND_

__device__ __forceinline__ float gelu_exact(float x){
  return 0.5f * x * (1.0f + erff(x * 0.70710678118654752440f));
}

__device__ __forceinline__ unsigned long long packv(float x, int col){
  unsigned u = __float_as_uint(x);
  u = (u & 0x80000000u) ? ~u : (u | 0x80000000u);   // order-preserving float->uint
  return (((unsigned long long)u) << 16) | (unsigned long long)(65535 - col); // tie -> lower col wins
}

__device__ __forceinline__ float unpack_val(unsigned long long g){
  unsigned u = (unsigned)(g >> 16);
  unsigned bits = (u & 0x80000000u) ? (u & 0x7FFFFFFFu) : ~u;
  return __uint_as_float(bits);
}

__device__ __forceinline__ int unpack_col(unsigned long long g){
  return 65535 - (int)(g & 0xFFFFULL);
}

__device__ __forceinline__ unsigned long long block_max_u64(unsigned long long m,
                                                            unsigned long long* sm, int nwaves){
  #pragma unroll
  for (int off = 1; off < 64; off <<= 1){
    unsigned long long o = __shfl_xor(m, off);
    if (o > m) m = o;
  }
  const int tid = threadIdx.x;
  if ((tid & 63) == 0) sm[tid >> 6] = m;
  __syncthreads();
  unsigned long long g = sm[0];
  for (int w = 1; w < nwaves; ++w) if (sm[w] > g) g = sm[w];
  __syncthreads();
  return g;
}

typedef const __attribute__((address_space(1))) void* gas_t;
typedef __attribute__((address_space(3))) void* las_t;
__device__ __forceinline__ void gload_lds16(const float* g, float* l){
  __builtin_amdgcn_global_load_lds((gas_t)(const void*)g, (las_t)(void*)l, 16, 0, 0);
}

// K1: partial sums for the two small GEMMs (R14, unchanged).
__global__ __launch_bounds__(256)
void mlp_partial(const float* __restrict__ hidf, const float* __restrict__ hidl5,
                 const float* __restrict__ W1, const float* __restrict__ Wext,
                 float* __restrict__ partial){
  const int jl  = threadIdx.x & 63;
  const int bq  = threadIdx.x >> 6;
  const int col = blockIdx.x * 64 + jl;
  const int chunk = blockIdx.y;
  const float* W; const float* X; int Kfull, k0;
  if (chunk < 8){ W = W1;   X = hidf;  Kfull = HID_;  k0 = chunk * 96; }
  else          { W = Wext; X = hidl5; Kfull = OUT5_; k0 = (chunk - 8) * 96; }
  const float* Wp = W + (size_t)k0 * HDIM_ + col;
  const float* Xp = X + (size_t)(bq * 8) * Kfull + k0;
  float acc[8] = {0,0,0,0,0,0,0,0};
  for (int k = 0; k < 96; k += 8){
    float wv[8];
    #pragma unroll
    for (int u = 0; u < 8; ++u) wv[u] = Wp[(size_t)(k + u) * HDIM_];
    #pragma unroll
    for (int i = 0; i < 8; ++i){
      const float4 xa = *reinterpret_cast<const float4*>(Xp + (size_t)i * Kfull + k);
      const float4 xb = *reinterpret_cast<const float4*>(Xp + (size_t)i * Kfull + k + 4);
      acc[i] = fmaf(xa.x, wv[0], acc[i]);
      acc[i] = fmaf(xa.y, wv[1], acc[i]);
      acc[i] = fmaf(xa.z, wv[2], acc[i]);
      acc[i] = fmaf(xa.w, wv[3], acc[i]);
      acc[i] = fmaf(xb.x, wv[4], acc[i]);
      acc[i] = fmaf(xb.y, wv[5], acc[i]);
      acc[i] = fmaf(xb.z, wv[6], acc[i]);
      acc[i] = fmaf(xb.w, wv[7], acc[i]);
    }
  }
  float* outp = partial + (size_t)chunk * (B_ * HDIM_) + (size_t)(bq * 8) * HDIM_ + col;
  #pragma unroll
  for (int i = 0; i < 8; ++i) outp[(size_t)i * HDIM_] = acc[i];
}

// K2: reduce chunks + bias + exact GELU (R14, unchanged).
__global__ __launch_bounds__(256)
void act_kernel(const float* __restrict__ partial, const float* __restrict__ b1,
                const float* __restrict__ bext, float* __restrict__ hT,
                float* __restrict__ h_ext){
  const int t = blockIdx.x * 256 + threadIdx.x;
  if (t < B_ * HDIM_){
    const int b = t >> 9, j = t & 511;
    float s = b1[j];
    #pragma unroll
    for (int c = 0; c < 8; ++c) s += partial[c * (B_ * HDIM_) + t];
    hT[j * B_ + b] = gelu_exact(s);
  } else {
    const int u = t - B_ * HDIM_;
    const int j = u & 511;
    float s = bext[j];
    #pragma unroll
    for (int c = 8; c < 32; ++c) s += partial[c * (B_ * HDIM_) + u];
    h_ext[u] = gelu_exact(s);
  }
}

// K3: meta GEMM. CHANGE vs R14: CKM 32->64 (8 chunks, half the barriers),
// 2x64KB double-buffer, wait-own-vmcnt(0) -> barrier -> stage(c+1) -> compute(c).
// Wave (r,q): rows r*8..+8, k-quarter q (16 rows of the 64-row chunk). Lane: 4 cols.
#define CKM_ 64
__global__ __launch_bounds__(1024, 4)
void meta_gemm(const float* __restrict__ hT, const float* __restrict__ W2,
               const float* __restrict__ b2, float* __restrict__ logits){
  __shared__ float smem[2][CKM_ * 256];   // 2 x 64 KB = 128 KB
  const int tid = threadIdx.x;
  const int l   = tid & 63;
  const int w   = tid >> 6;               // 0..15
  const int r   = w & 3;                  // row-group
  const int q   = w >> 2;                 // k-quarter
  const int colBase = blockIdx.x * 256;
  const int sb8  = __builtin_amdgcn_readfirstlane(r * 8);
  const int kb16 = __builtin_amdgcn_readfirstlane(q * 16);  // uniform k-offset

  float acc[8][4];
  #pragma unroll
  for (int i = 0; i < 8; ++i)
    #pragma unroll
    for (int j = 0; j < 4; ++j) acc[i][j] = 0.f;

  // stage chunk c: 64 rows x 256 cols; wave stages rows 4w..4w+3 (1 KB each).
  auto stage = [&](int c, int bf){
    #pragma unroll
    for (int i = 0; i < 4; ++i){
      const int row = 4 * w + i;
      gload_lds16(W2 + (size_t)(c * CKM_ + row) * NC_ + colBase + l * 4,
                  &smem[bf][row * 256]);
    }
  };

  auto compute = [&](int c, int bf){
    const float* __restrict__ hbase = hT + (size_t)(c * CKM_ + kb16) * B_ + sb8;
    #pragma unroll
    for (int kk = 0; kk < 16; ++kk){
      const float4 wv = *reinterpret_cast<const float4*>(&smem[bf][(kb16 + kk) * 256 + l * 4]);
      const float4 h0 = *reinterpret_cast<const float4*>(hbase + kk * B_);
      const float4 h1 = *reinterpret_cast<const float4*>(hbase + kk * B_ + 4);
      const float hv[8] = {h0.x, h0.y, h0.z, h0.w, h1.x, h1.y, h1.z, h1.w};
      #pragma unroll
      for (int row = 0; row < 8; ++row){
        acc[row][0] = fmaf(hv[row], wv.x, acc[row][0]);
        acc[row][1] = fmaf(hv[row], wv.y, acc[row][1]);
        acc[row][2] = fmaf(hv[row], wv.z, acc[row][2]);
        acc[row][3] = fmaf(hv[row], wv.w, acc[row][3]);
      }
    }
  };

  stage(0, 0);
  for (int c = 0; c < HDIM_ / CKM_; ++c){          // 8 chunks
    asm volatile("s_waitcnt vmcnt(0)" ::: "memory"); // own stage(c) loads landed
    __builtin_amdgcn_s_barrier();                    // chunk c fully visible; compute(c-1) done everywhere
    if (c + 1 < HDIM_ / CKM_) stage(c + 1, (c + 1) & 1); // overlaps compute(c)
    compute(c, c & 1);
  }
  __syncthreads();   // all compute done before reusing smem[0] for reduction

  // cross-quarter reduction through smem[0] (32 rows x 256 cols), 3 rounds.
  #pragma unroll
  for (int qq = 1; qq <= 3; ++qq){
    if (q == qq){
      #pragma unroll
      for (int row = 0; row < 8; ++row){
        float4 t; t.x = acc[row][0]; t.y = acc[row][1]; t.z = acc[row][2]; t.w = acc[row][3];
        *reinterpret_cast<float4*>(&smem[0][(r * 8 + row) * 256 + l * 4]) = t;
      }
    }
    __syncthreads();
    if (q == 0){
      #pragma unroll
      for (int row = 0; row < 8; ++row){
        const float4 t = *reinterpret_cast<const float4*>(&smem[0][(r * 8 + row) * 256 + l * 4]);
        acc[row][0] += t.x; acc[row][1] += t.y; acc[row][2] += t.z; acc[row][3] += t.w;
      }
    }
    __syncthreads();
  }

  if (q == 0){
    const float4 bb = *reinterpret_cast<const float4*>(b2 + colBase + l * 4);
    #pragma unroll
    for (int row = 0; row < 8; ++row){
      float4 o;
      o.x = acc[row][0] + bb.x; o.y = acc[row][1] + bb.y;
      o.z = acc[row][2] + bb.z; o.w = acc[row][3] + bb.w;
      *reinterpret_cast<float4*>(logits + (size_t)(sb8 + row) * NC_ + colBase + l * 4) = o;
    }
  }
}

// K4: per-(row, 8192-col segment) top-10 (R4, unchanged).
__global__ __launch_bounds__(256)
void topk_seg(const float* __restrict__ logits, float* __restrict__ segv,
              int* __restrict__ segi){
  __shared__ unsigned long long sm[4];
  const int b   = blockIdx.x >> 3;
  const int seg = blockIdx.x & 7;
  const int tid = threadIdx.x;
  const float* row = logits + (size_t)b * NC_ + seg * 8192;
  float v[10]; int ix[10];
  #pragma unroll
  for (int r = 0; r < 10; ++r){ v[r] = -INFINITY; ix[r] = -1; }
  for (int s = 0; s < 32; ++s){
    const int j = s * 256 + tid;
    const float x = row[j];
    if (x > v[9]){
      v[9] = x; ix[9] = seg * 8192 + j;
      #pragma unroll
      for (int p = 9; p > 0; --p){
        if (v[p] > v[p-1]){
          float tv = v[p]; v[p] = v[p-1]; v[p-1] = tv;
          int   ti = ix[p]; ix[p] = ix[p-1]; ix[p-1] = ti;
        }
      }
    }
  }
  for (int r = 0; r < 10; ++r){
    unsigned long long mp = (ix[0] >= 0) ? packv(v[0], ix[0]) : 0ULL;
    unsigned long long g  = block_max_u64(mp, sm, 4);
    if (mp == g && mp != 0ULL){
      #pragma unroll
      for (int q = 0; q < 9; ++q){ v[q] = v[q+1]; ix[q] = ix[q+1]; }
      v[9] = -INFINITY; ix[9] = -1;
    }
    if (tid == 0){
      segv[blockIdx.x * 10 + r] = unpack_val(g);
      segi[blockIdx.x * 10 + r] = unpack_col(g);
    }
  }
}

// K5: merge 8 segment top-10s -> global top-10 per row (R4, unchanged).
__global__ __launch_bounds__(128)
void topk_merge(const float* __restrict__ segv, const int* __restrict__ segi,
                int* __restrict__ tk_idx, float* __restrict__ tk_score){
  __shared__ unsigned long long sm[2];
  const int b   = blockIdx.x;
  const int tid = threadIdx.x;
  unsigned long long mp = 0ULL;
  if (tid < 80) mp = packv(segv[b * 80 + tid], segi[b * 80 + tid]);
  for (int r = 0; r < 10; ++r){
    unsigned long long g = block_max_u64(mp, sm, 2);
    if (mp == g && mp != 0ULL) mp = 0ULL;   // consumed
    if (tid == 0){
      tk_idx[b * TOPK_ + r]   = unpack_col(g);
      tk_score[b * TOPK_ + r] = 1.0f / (1.0f + expf(-unpack_val(g)));
    }
  }
}

// K6: candidate gather + dot + outputs (R4, unchanged).
__global__ __launch_bounds__(256)
void cand_kernel(const int* __restrict__ gy, const float* __restrict__ embed,
                 const float* __restrict__ h_ext, const int* __restrict__ tk_idx,
                 const float* __restrict__ tk_score, float* __restrict__ out_f){
  const int wid  = threadIdx.x >> 6;
  const int lane = threadIdx.x & 63;
  const int gw   = blockIdx.x * 4 + wid;
  const int b    = gw / CAND_;
  const int c    = gw - b * CAND_;
  const int t    = c / MAXG_;
  const int g    = c - t * MAXG_;

  const unsigned int* gyw = (const unsigned int*)gy;
  const unsigned int probe = gyw[2 * (size_t)(gw * 64 + lane) + 1];
  const bool is64 = (__ballot(probe != 0u) == 0ULL);   // int64 vs int32 group_y layout

  const int idx  = tk_idx[b * TOPK_ + t];
  const size_t li = (size_t)idx * MAXG_ + g;
  const int cand = is64 ? (int)((const long long*)gy)[li] : gy[li];

  const float* erow = embed + (size_t)cand * HDIM_;
  const float* hrow = h_ext + (size_t)b * HDIM_;
  const float4 e0 = reinterpret_cast<const float4*>(erow)[lane];
  const float4 e1 = reinterpret_cast<const float4*>(erow)[lane + 64];
  const float4 h0 = reinterpret_cast<const float4*>(hrow)[lane];
  const float4 h1 = reinterpret_cast<const float4*>(hrow)[lane + 64];
  float s = e0.x*h0.x + e0.y*h0.y + e0.z*h0.z + e0.w*h0.w
          + e1.x*h1.x + e1.y*h1.y + e1.z*h1.z + e1.w*h1.w;
  #pragma unroll
  for (int off = 1; off < 64; off <<= 1) s += __shfl_xor(s, off);
  if (lane == 0){
    const float cs   = (s == 0.0f) ? 0.0f : 1.0f / (1.0f + expf(-s));
    const float comb = cs * ((cand != NL_) ? tk_score[b * TOPK_ + t] : 0.0f);
    const int o = b * CAND_ + c;
    __hip_bfloat16* outs = (__hip_bfloat16*)(out_f + NOUT_);
    __hip_bfloat16* outm = outs + NOUT_;
    out_f[o] = (float)cand;
    outs[o]  = __float2bfloat16(cs);
    outm[o]  = __float2bfloat16(comb);
  }
}

extern "C" void kernel_launch(void* const* d_in, const int* in_sizes, int n_in,
                              void* d_out, int out_size, void* d_ws, size_t ws_size,
                              hipStream_t stream){
  const float* hidf  = (const float*)d_in[0];
  const float* hidl5 = (const float*)d_in[1];
  const float* W1    = (const float*)d_in[2];
  const float* b1    = (const float*)d_in[3];
  const float* W2    = (const float*)d_in[4];
  const float* b2    = (const float*)d_in[5];
  const float* Wext  = (const float*)d_in[6];
  const float* bext  = (const float*)d_in[7];
  const float* embed = (const float*)d_in[8];
  const int*   gy    = (const int*)d_in[9];
  float* out_f = (float*)d_out;

  float* ws      = (float*)d_ws;
  float* logits  = ws;                          // [32][65536] f32 (8 MiB)
  float* partial = ws;                          // aliased: dead before meta_gemm
  float* hT      = logits + (size_t)B_ * NC_;   // [512][32]
  float* h_ext   = hT + B_ * HDIM_;             // [32][512]
  float* segv    = h_ext + B_ * HDIM_;          // 2560
  int*   segi    = (int*)(segv + 2560);         // 2560
  float* tk_sc   = (float*)(segi + 2560);       // 320
  int*   tk_ix   = (int*)(tk_sc + 320);         // 320

  mlp_partial<<<dim3(8, 32), 256, 0, stream>>>(hidf, hidl5, W1, Wext, partial);
  act_kernel <<<128, 256, 0, stream>>>(partial, b1, bext, hT, h_ext);
  meta_gemm  <<<NC_ / 256, 1024, 0, stream>>>(hT, W2, b2, logits);
  topk_seg   <<<B_ * 8, 256, 0, stream>>>(logits, segv, segi);
  topk_merge <<<B_, 128, 0, stream>>>(segv, segi, tk_ix, tk_sc);
  cand_kernel<<<NOUT_ / 4, 256, 0, stream>>>(gy, embed, h_ext, tk_ix, tk_sc, out_f);
}

// Round 17
// 74.466 us; speedup vs baseline: 1.3471x; 1.1664x over previous
//
#include <hip/hip_runtime.h>
#include <hip/hip_bf16.h>
#include <math.h>

#define B_     32
#define HID_   768
#define OUT5_  2304
#define HDIM_  512
#define NC_    65536
#define MAXG_  11
#define NL_    670091
#define TOPK_  10
#define CAND_  110   // TOPK_*MAXG_
#define NOUT_  3520  // B_*CAND_
#define NSTR_  256   // 256-col stripes

__device__ __forceinline__ float gelu_exact(float x){
  return 0.5f * x * (1.0f + erff(x * 0.70710678118654752440f));
}

__device__ __forceinline__ unsigned long long packv(float x, int col){
  unsigned u = __float_as_uint(x);
  u = (u & 0x80000000u) ? ~u : (u | 0x80000000u);   // order-preserving float->uint
  return (((unsigned long long)u) << 16) | (unsigned long long)(65535 - col); // tie -> lower col wins
}

__device__ __forceinline__ float unpack_val(unsigned long long g){
  unsigned u = (unsigned)(g >> 16);
  unsigned bits = (u & 0x80000000u) ? (u & 0x7FFFFFFFu) : ~u;
  return __uint_as_float(bits);
}

__device__ __forceinline__ int unpack_col(unsigned long long g){
  return 65535 - (int)(g & 0xFFFFULL);
}

__device__ __forceinline__ unsigned long long wave_max_u64(unsigned long long m){
  #pragma unroll
  for (int off = 1; off < 64; off <<= 1){
    unsigned long long o = __shfl_xor(m, off);
    if (o > m) m = o;
  }
  return m;
}

__device__ __forceinline__ unsigned long long block_max_u64(unsigned long long m,
                                                            unsigned long long* sm, int nwaves){
  m = wave_max_u64(m);
  const int tid = threadIdx.x;
  if ((tid & 63) == 0) sm[tid >> 6] = m;
  __syncthreads();
  unsigned long long g = sm[0];
  for (int w = 1; w < nwaves; ++w) if (sm[w] > g) g = sm[w];
  __syncthreads();
  return g;
}

typedef const __attribute__((address_space(1))) void* gas_t;
typedef __attribute__((address_space(3))) void* las_t;
__device__ __forceinline__ void gload_lds16(const float* g, float* l){
  __builtin_amdgcn_global_load_lds((gas_t)(const void*)g, (las_t)(void*)l, 16, 0, 0);
}

// K1: partial sums for the two small GEMMs (R14, unchanged).
__global__ __launch_bounds__(256)
void mlp_partial(const float* __restrict__ hidf, const float* __restrict__ hidl5,
                 const float* __restrict__ W1, const float* __restrict__ Wext,
                 float* __restrict__ partial){
  const int jl  = threadIdx.x & 63;
  const int bq  = threadIdx.x >> 6;
  const int col = blockIdx.x * 64 + jl;
  const int chunk = blockIdx.y;
  const float* W; const float* X; int Kfull, k0;
  if (chunk < 8){ W = W1;   X = hidf;  Kfull = HID_;  k0 = chunk * 96; }
  else          { W = Wext; X = hidl5; Kfull = OUT5_; k0 = (chunk - 8) * 96; }
  const float* Wp = W + (size_t)k0 * HDIM_ + col;
  const float* Xp = X + (size_t)(bq * 8) * Kfull + k0;
  float acc[8] = {0,0,0,0,0,0,0,0};
  for (int k = 0; k < 96; k += 8){
    float wv[8];
    #pragma unroll
    for (int u = 0; u < 8; ++u) wv[u] = Wp[(size_t)(k + u) * HDIM_];
    #pragma unroll
    for (int i = 0; i < 8; ++i){
      const float4 xa = *reinterpret_cast<const float4*>(Xp + (size_t)i * Kfull + k);
      const float4 xb = *reinterpret_cast<const float4*>(Xp + (size_t)i * Kfull + k + 4);
      acc[i] = fmaf(xa.x, wv[0], acc[i]);
      acc[i] = fmaf(xa.y, wv[1], acc[i]);
      acc[i] = fmaf(xa.z, wv[2], acc[i]);
      acc[i] = fmaf(xa.w, wv[3], acc[i]);
      acc[i] = fmaf(xb.x, wv[4], acc[i]);
      acc[i] = fmaf(xb.y, wv[5], acc[i]);
      acc[i] = fmaf(xb.z, wv[6], acc[i]);
      acc[i] = fmaf(xb.w, wv[7], acc[i]);
    }
  }
  float* outp = partial + (size_t)chunk * (B_ * HDIM_) + (size_t)(bq * 8) * HDIM_ + col;
  #pragma unroll
  for (int i = 0; i < 8; ++i) outp[(size_t)i * HDIM_] = acc[i];
}

// K2: reduce chunks + bias + exact GELU (R14, unchanged).
__global__ __launch_bounds__(256)
void act_kernel(const float* __restrict__ partial, const float* __restrict__ b1,
                const float* __restrict__ bext, float* __restrict__ hT,
                float* __restrict__ h_ext){
  const int t = blockIdx.x * 256 + threadIdx.x;
  if (t < B_ * HDIM_){
    const int b = t >> 9, j = t & 511;
    float s = b1[j];
    #pragma unroll
    for (int c = 0; c < 8; ++c) s += partial[c * (B_ * HDIM_) + t];
    hT[j * B_ + b] = gelu_exact(s);
  } else {
    const int u = t - B_ * HDIM_;
    const int j = u & 511;
    float s = bext[j];
    #pragma unroll
    for (int c = 8; c < 32; ++c) s += partial[c * (B_ * HDIM_) + u];
    h_ext[u] = gelu_exact(s);
  }
}

// K3: meta GEMM — R14's proven CKM=32 triple-buffer vmcnt(2) pipeline,
// + per-(row,stripe) packed-max epilogue (blockmax) for topk pruning.
#define CKM_ 32
__global__ __launch_bounds__(1024, 4)
void meta_gemm(const float* __restrict__ hT, const float* __restrict__ W2,
               const float* __restrict__ b2, float* __restrict__ logits,
               unsigned long long* __restrict__ blockmax){
  __shared__ float smem[3][CKM_ * 256];   // 3 x 32 KB = 96 KB
  const int tid = threadIdx.x;
  const int l   = tid & 63;
  const int w   = tid >> 6;               // 0..15
  const int r   = w & 3;                  // row-group
  const int q   = w >> 2;                 // k-quarter
  const int colBase = blockIdx.x * 256;
  const int sb8 = __builtin_amdgcn_readfirstlane(r * 8);
  const int kb8 = __builtin_amdgcn_readfirstlane(q * 8);   // uniform k-offset

  float acc[8][4];
  #pragma unroll
  for (int i = 0; i < 8; ++i)
    #pragma unroll
    for (int j = 0; j < 4; ++j) acc[i][j] = 0.f;

  auto stage = [&](int c, int bf){
    #pragma unroll
    for (int i = 0; i < 2; ++i){
      const int row = 2 * w + i;
      gload_lds16(W2 + (size_t)(c * CKM_ + row) * NC_ + colBase + l * 4,
                  &smem[bf][row * 256]);
    }
  };

  auto compute = [&](int c, int bf){
    const float* __restrict__ hbase = hT + (size_t)(c * CKM_ + kb8) * B_ + sb8;
    #pragma unroll
    for (int kk = 0; kk < 8; ++kk){
      const float4 wv = *reinterpret_cast<const float4*>(&smem[bf][(kb8 + kk) * 256 + l * 4]);
      const float4 h0 = *reinterpret_cast<const float4*>(hbase + kk * B_);
      const float4 h1 = *reinterpret_cast<const float4*>(hbase + kk * B_ + 4);
      const float hv[8] = {h0.x, h0.y, h0.z, h0.w, h1.x, h1.y, h1.z, h1.w};
      #pragma unroll
      for (int row = 0; row < 8; ++row){
        acc[row][0] = fmaf(hv[row], wv.x, acc[row][0]);
        acc[row][1] = fmaf(hv[row], wv.y, acc[row][1]);
        acc[row][2] = fmaf(hv[row], wv.z, acc[row][2]);
        acc[row][3] = fmaf(hv[row], wv.w, acc[row][3]);
      }
    }
  };

  stage(0, 0);
  stage(1, 1);
  for (int c = 0; c < HDIM_ / CKM_ - 1; ++c){   // c = 0..14
    asm volatile("s_waitcnt vmcnt(2)" ::: "memory");  // chunk c landed; c+1 in flight
    __builtin_amdgcn_s_barrier();
    if (c + 2 < HDIM_ / CKM_) stage(c + 2, (c + 2) % 3);
    compute(c, c % 3);
  }
  asm volatile("s_waitcnt vmcnt(0)" ::: "memory");
  __builtin_amdgcn_s_barrier();
  compute(HDIM_ / CKM_ - 1, (HDIM_ / CKM_ - 1) % 3);
  __syncthreads();

  // cross-quarter reduction through smem[0], 3 rounds.
  #pragma unroll
  for (int qq = 1; qq <= 3; ++qq){
    if (q == qq){
      #pragma unroll
      for (int row = 0; row < 8; ++row){
        float4 t; t.x = acc[row][0]; t.y = acc[row][1]; t.z = acc[row][2]; t.w = acc[row][3];
        *reinterpret_cast<float4*>(&smem[0][(r * 8 + row) * 256 + l * 4]) = t;
      }
    }
    __syncthreads();
    if (q == 0){
      #pragma unroll
      for (int row = 0; row < 8; ++row){
        const float4 t = *reinterpret_cast<const float4*>(&smem[0][(r * 8 + row) * 256 + l * 4]);
        acc[row][0] += t.x; acc[row][1] += t.y; acc[row][2] += t.z; acc[row][3] += t.w;
      }
    }
    __syncthreads();
  }

  if (q == 0){
    const float4 bb = *reinterpret_cast<const float4*>(b2 + colBase + l * 4);
    #pragma unroll
    for (int row = 0; row < 8; ++row){
      float4 o;
      o.x = acc[row][0] + bb.x; o.y = acc[row][1] + bb.y;
      o.z = acc[row][2] + bb.z; o.w = acc[row][3] + bb.w;
      *reinterpret_cast<float4*>(logits + (size_t)(sb8 + row) * NC_ + colBase + l * 4) = o;
      // blockmax epilogue: max packed key of this row's 256-col stripe
      unsigned long long k0 = packv(o.x, colBase + l * 4);
      unsigned long long k1 = packv(o.y, colBase + l * 4 + 1);
      unsigned long long k2 = packv(o.z, colBase + l * 4 + 2);
      unsigned long long k3 = packv(o.w, colBase + l * 4 + 3);
      unsigned long long m01 = k0 > k1 ? k0 : k1;
      unsigned long long m23 = k2 > k3 ? k2 : k3;
      unsigned long long m = wave_max_u64(m01 > m23 ? m01 : m23);
      if (l == 0) blockmax[(size_t)(sb8 + row) * NSTR_ + blockIdx.x] = m;
    }
  }
}

// K4 (new): per-row { select 10 winning stripes from 256 blockmax keys |
// exact top-10 over the 2560 surviving logits }. 32 blocks x 256 thr.
__global__ __launch_bounds__(256)
void stripe_topk(const float* __restrict__ logits,
                 const unsigned long long* __restrict__ blockmax,
                 int* __restrict__ tk_idx, float* __restrict__ tk_score){
  __shared__ unsigned long long sm[4];
  __shared__ int win[TOPK_];
  const int b   = blockIdx.x;
  const int tid = threadIdx.x;

  // Phase 1: 10 stripes with largest packed max (keys distinct -> unique owner).
  unsigned long long mp = blockmax[(size_t)b * NSTR_ + tid];
  for (int r = 0; r < 10; ++r){
    unsigned long long g = block_max_u64(mp, sm, 4);
    if (mp == g && g != 0ULL) mp = 0ULL;
    if (tid == 0) win[r] = unpack_col(g) >> 8;   // stripe id (256 cols/stripe)
    __syncthreads();
  }

  // Phase 2: exact top-10 over 10 stripes x 256 cols (tie-break identical).
  const float* row = logits + (size_t)b * NC_;
  float v[10]; int ix[10];
  #pragma unroll
  for (int r = 0; r < 10; ++r){ v[r] = -INFINITY; ix[r] = -1; }
  #pragma unroll
  for (int i = 0; i < 10; ++i){
    const int col = win[i] * 256 + tid;
    const float x = row[col];
    if (x > v[9]){
      v[9] = x; ix[9] = col;
      #pragma unroll
      for (int p = 9; p > 0; --p){
        if (v[p] > v[p-1]){
          float tv = v[p]; v[p] = v[p-1]; v[p-1] = tv;
          int   ti = ix[p]; ix[p] = ix[p-1]; ix[p-1] = ti;
        }
      }
    }
  }
  for (int r = 0; r < 10; ++r){
    unsigned long long mp2 = (ix[0] >= 0) ? packv(v[0], ix[0]) : 0ULL;
    unsigned long long g = block_max_u64(mp2, sm, 4);
    if (mp2 == g && mp2 != 0ULL){
      #pragma unroll
      for (int p = 0; p < 9; ++p){ v[p] = v[p+1]; ix[p] = ix[p+1]; }
      v[9] = -INFINITY; ix[9] = -1;
    }
    if (tid == 0){
      tk_idx[b * TOPK_ + r]   = unpack_col(g);
      tk_score[b * TOPK_ + r] = 1.0f / (1.0f + expf(-unpack_val(g)));
    }
  }
}

// K5: candidate gather + dot + outputs (R4, unchanged).
__global__ __launch_bounds__(256)
void cand_kernel(const int* __restrict__ gy, const float* __restrict__ embed,
                 const float* __restrict__ h_ext, const int* __restrict__ tk_idx,
                 const float* __restrict__ tk_score, float* __restrict__ out_f){
  const int wid  = threadIdx.x >> 6;
  const int lane = threadIdx.x & 63;
  const int gw   = blockIdx.x * 4 + wid;
  const int b    = gw / CAND_;
  const int c    = gw - b * CAND_;
  const int t    = c / MAXG_;
  const int g    = c - t * MAXG_;

  const unsigned int* gyw = (const unsigned int*)gy;
  const unsigned int probe = gyw[2 * (size_t)(gw * 64 + lane) + 1];
  const bool is64 = (__ballot(probe != 0u) == 0ULL);   // int64 vs int32 group_y layout

  const int idx  = tk_idx[b * TOPK_ + t];
  const size_t li = (size_t)idx * MAXG_ + g;
  const int cand = is64 ? (int)((const long long*)gy)[li] : gy[li];

  const float* erow = embed + (size_t)cand * HDIM_;
  const float* hrow = h_ext + (size_t)b * HDIM_;
  const float4 e0 = reinterpret_cast<const float4*>(erow)[lane];
  const float4 e1 = reinterpret_cast<const float4*>(erow)[lane + 64];
  const float4 h0 = reinterpret_cast<const float4*>(hrow)[lane];
  const float4 h1 = reinterpret_cast<const float4*>(hrow)[lane + 64];
  float s = e0.x*h0.x + e0.y*h0.y + e0.z*h0.z + e0.w*h0.w
          + e1.x*h1.x + e1.y*h1.y + e1.z*h1.z + e1.w*h1.w;
  #pragma unroll
  for (int off = 1; off < 64; off <<= 1) s += __shfl_xor(s, off);
  if (lane == 0){
    const float cs   = (s == 0.0f) ? 0.0f : 1.0f / (1.0f + expf(-s));
    const float comb = cs * ((cand != NL_) ? tk_score[b * TOPK_ + t] : 0.0f);
    const int o = b * CAND_ + c;
    __hip_bfloat16* outs = (__hip_bfloat16*)(out_f + NOUT_);
    __hip_bfloat16* outm = outs + NOUT_;
    out_f[o] = (float)cand;
    outs[o]  = __float2bfloat16(cs);
    outm[o]  = __float2bfloat16(comb);
  }
}

extern "C" void kernel_launch(void* const* d_in, const int* in_sizes, int n_in,
                              void* d_out, int out_size, void* d_ws, size_t ws_size,
                              hipStream_t stream){
  const float* hidf  = (const float*)d_in[0];
  const float* hidl5 = (const float*)d_in[1];
  const float* W1    = (const float*)d_in[2];
  const float* b1    = (const float*)d_in[3];
  const float* W2    = (const float*)d_in[4];
  const float* b2    = (const float*)d_in[5];
  const float* Wext  = (const float*)d_in[6];
  const float* bext  = (const float*)d_in[7];
  const float* embed = (const float*)d_in[8];
  const int*   gy    = (const int*)d_in[9];
  float* out_f = (float*)d_out;

  float* ws      = (float*)d_ws;
  float* logits  = ws;                          // [32][65536] f32 (8 MiB)
  float* partial = ws;                          // aliased: dead before meta_gemm
  float* hT      = logits + (size_t)B_ * NC_;   // [512][32]
  float* h_ext   = hT + B_ * HDIM_;             // [32][512]
  unsigned long long* blockmax =
      (unsigned long long*)(h_ext + B_ * HDIM_); // [32][256] u64 (64 KB)
  float* tk_sc   = (float*)(blockmax + (size_t)B_ * NSTR_);  // 320
  int*   tk_ix   = (int*)(tk_sc + 320);                      // 320

  mlp_partial<<<dim3(8, 32), 256, 0, stream>>>(hidf, hidl5, W1, Wext, partial);
  act_kernel <<<128, 256, 0, stream>>>(partial, b1, bext, hT, h_ext);
  meta_gemm  <<<NC_ / 256, 1024, 0, stream>>>(hT, W2, b2, logits, blockmax);
  stripe_topk<<<B_, 256, 0, stream>>>(logits, blockmax, tk_ix, tk_sc);
  cand_kernel<<<NOUT_ / 4, 256, 0, stream>>>(gy, embed, h_ext, tk_ix, tk_sc, out_f);
}